// Round 3
// baseline (315.092 us; speedup 1.0000x reference)
//
#include <hip/hip_runtime.h>
#include <hip/hip_cooperative_groups.h>
#include <math.h>

// DecodeSPM on gfx950 — round 7: single cooperative kernel (R6 resubmit —
// R6 never ran: GPU acquisition timeout). One added micro-opt: P1 caches the
// 4 sigmoid bit-patterns per thread in registers (threads persist across
// grid.sync), so P3 compact needs no second 4MB read / 1M-expf pass.
// Structure:
//   grid = 256 blocks x 1024 thr (co-resident: 62KB LDS, 16 waves/blk).
//   P0 zero hist -> P1 hist (cache bits) -> P2 cut (block 0) ->
//   P3 compact (register-cached bits) ->
//   P4 walk (block 0: per-bin sort + cell-hash frontier NMS, serial fallback
//   on overflow) -> P5 kp (block r handles root r, 34 lanes).
// Fallback: if cooperative launch is rejected, run the verified R5
// 6-dispatch path unchanged.

#define SS 1024
#define MAXR 256
#define NBIN 16384
#define CAP 1024
#define TARGET 768u
#define B0 0x3F4CCCCEu     // smallest f32 bit pattern with s > 0.8f
#define KEYB0 0xBF4CCCCEu  // B0 | 0x80000000
#define CONFL_MAX 8
#define CELL_CAP 8

namespace cg = cooperative_groups;

struct WS {
  unsigned int hist[NBIN];
  unsigned int dstOff[NBIN];
  unsigned int cutBits;
  unsigned int candCount;
  int nValid;
  int pad0;
  int rootX[MAXR];
  int rootY[MAXR];
  unsigned long long cand[CAP];
};

__device__ __forceinline__ float sigm(float v) {
  return 1.0f / (1.0f + expf(-v));
}

// ---------------------------------------------------------------- fused ----
__global__ __launch_bounds__(1024) void spm_fused(const float* __restrict__ x,
                                                  WS* __restrict__ w,
                                                  float* __restrict__ out) {
  cg::grid_group grid = cg::this_grid();
  const int tid = threadIdx.x;
  const int bid = blockIdx.x;
  const int gtid = (bid << 10) + tid;  // 0..262143

  // shared state (block 0 uses most of it; ~62 KB total)
  __shared__ unsigned int sc[1024];
  __shared__ unsigned long long s[CAP];
  __shared__ unsigned short binA[CAP];
  __shared__ unsigned int pxy[CAP];
  __shared__ int cellCnt[1024];                      // 32x32 grid of 32px cells
  __shared__ unsigned short cellList[1024 * CELL_CAP];
  __shared__ unsigned short confl[CAP * CONFL_MAX];  // higher-ranked conflicts
  __shared__ unsigned char ccnt[CAP];
  __shared__ unsigned char state[CAP];               // 0 undec, 1 acc, 2 rej
  __shared__ int scv[CAP];
  __shared__ unsigned int rootPid[MAXR];
  __shared__ int nVsh;
  __shared__ int undecSh;
  __shared__ int ovfSh;

  // ---- P0: zero histogram ----
  if (gtid < NBIN) w->hist[gtid] = 0;
  grid.sync();

  // ---- P1: histogram of conf bits>>8 (coalesced, stride 262144);
  //          cache survivor bit-patterns in registers for P3 ----
  unsigned int bb[4];
#pragma unroll
  for (int j = 0; j < 4; ++j) {
    float v = x[(j << 18) + gtid];
    float sg = sigm(v);
    bb[j] = 0u;
    if (sg > 0.8f) {
      unsigned int b = __float_as_uint(sg);
      bb[j] = b;
      unsigned int bin = (b - B0) >> 8;
      if (bin > NBIN - 1) bin = NBIN - 1;
      atomicAdd(&w->hist[bin], 1u);
    }
  }
  grid.sync();

  // ---- P2: suffix-scan cutoff (block 0 only) ----
  if (bid == 0) {
    const int t = tid;
    const int base = t << 4;
    unsigned int cnt[16];
    unsigned int chunkSum = 0;
#pragma unroll
    for (int i = 0; i < 16; ++i) { cnt[i] = w->hist[base + i]; chunkSum += cnt[i]; }
    sc[t] = chunkSum;
    __syncthreads();
    for (int off = 1; off < 1024; off <<= 1) {
      unsigned int v = sc[t] + ((t + off < 1024) ? sc[t + off] : 0u);
      __syncthreads();
      sc[t] = v;
      __syncthreads();
    }
    // sc[t] = inclusive suffix over chunks t..1023
    const unsigned int tailBeyond = (t < 1023) ? sc[t + 1] : 0u;
    unsigned int run = tailBeyond;
    unsigned int sufL[16];
    for (int i = 15; i >= 0; --i) {
      w->dstOff[base + i] = run;   // #keys in bins > base+i (descending order)
      run += cnt[i];
      sufL[i] = run;               // #keys in bins >= base+i
    }
    __shared__ unsigned int cutBinSh;
    __shared__ unsigned int cnSh;
    if (t == 0) {
      cutBinSh = 0;
      unsigned int total = sufL[0];
      cnSh = (total < CAP) ? total : CAP;
    }
    __syncthreads();
#pragma unroll
    for (int i = 0; i < 16; ++i) {
      unsigned int nxt = (i < 15) ? sufL[i + 1] : tailBeyond;
      if (sufL[i] >= TARGET && nxt < TARGET) {
        cutBinSh = (unsigned)(base + i);
        cnSh = (sufL[i] < CAP) ? sufL[i] : CAP;
      }
    }
    __syncthreads();
    if (t == 0) {
      w->cutBits = B0 + (cutBinSh << 8);
      w->candCount = cnSh;
    }
  }
  grid.sync();

  // ---- P3: compact survivors (register-cached bits; no x re-read) ----
  {
    const unsigned int cb = w->cutBits;
#pragma unroll
    for (int j = 0; j < 4; ++j) {
      unsigned int b = bb[j];
      if (b >= cb) {  // cb >= B0 > 0, so b==0 (below thr) never passes
        int p = (j << 18) + gtid;
        unsigned int bin = (b - B0) >> 8;
        if (bin > NBIN - 1) bin = NBIN - 1;
        unsigned int pos = atomicAdd(&w->dstOff[bin], 1u);
        if (pos < CAP)
          w->cand[pos] =
              ((unsigned long long)(b | 0x80000000u) << 32) | (unsigned int)(~p);
      }
    }
  }
  grid.sync();

  // ---- P4: sort + exact parallel greedy NMS (block 0 only) ----
  if (bid == 0) {
    unsigned int cn = w->candCount;
    if (cn > CAP) cn = CAP;
    if ((unsigned)tid < cn) {
      unsigned long long k = w->cand[tid];
      s[tid] = k;
      binA[tid] = (unsigned short)(((unsigned int)(k >> 32) - KEYB0) >> 8);
    } else {
      s[tid] = 0ULL;
      binA[tid] = 0xFFFFu;
    }
    if (tid == 0) ovfSh = 0;
    cellCnt[tid] = 0;
    __syncthreads();
    // per-bin insertion sort (descending, full 64-bit key). Disjoint segments;
    // binA is read-only past this point, so boundary checks are race-free.
    const bool isStart =
        ((unsigned)tid < cn) && (tid == 0 || binA[tid] != binA[tid - 1]);
    if (isStart) {
      const unsigned short mybin = binA[tid];
      int e = tid + 1;
      while (e < (int)cn && binA[e] == mybin) ++e;
      for (int j = tid + 1; j < e; ++j) {
        unsigned long long key = s[j];
        int i2 = j - 1;
        while (i2 >= tid && s[i2] < key) { s[i2 + 1] = s[i2]; --i2; }
        s[i2 + 1] = key;
      }
    }
    __syncthreads();
    // decode positions; hash into 32px cells (radius 10 spans <=2 cells/axis)
    int myx = 0, myy = 0;
    if ((unsigned)tid < cn) {
      unsigned int pid = ~(unsigned int)s[tid];
      myx = (int)(pid & 1023u);
      myy = (int)(pid >> 10);
      pxy[tid] = (unsigned int)myx | ((unsigned int)myy << 16);
      int cell = ((myy >> 5) << 5) | (myx >> 5);
      int pos = atomicAdd(&cellCnt[cell], 1);
      if (pos < CELL_CAP) cellList[cell * CELL_CAP + pos] = (unsigned short)tid;
      else ovfSh = 1;
    }
    __syncthreads();
    // conflict lists: higher-ranked (smaller index) candidates within d^2<=100
    int nc = 0;
    if ((unsigned)tid < cn) {
      int cy0 = (myy >= 10) ? ((myy - 10) >> 5) : 0;
      int cy1 = (((myy + 10) < 1023) ? (myy + 10) : 1023) >> 5;
      int cx0 = (myx >= 10) ? ((myx - 10) >> 5) : 0;
      int cx1 = (((myx + 10) < 1023) ? (myx + 10) : 1023) >> 5;
      for (int cyc = cy0; cyc <= cy1; ++cyc) {
        for (int cxc = cx0; cxc <= cx1; ++cxc) {
          int cell = (cyc << 5) | cxc;
          int cnt2 = cellCnt[cell];
          if (cnt2 > CELL_CAP) cnt2 = CELL_CAP;
          for (int e = 0; e < cnt2; ++e) {
            int j = (int)cellList[cell * CELL_CAP + e];
            if (j < tid) {
              unsigned int p = pxy[j];
              int dx = myx - (int)(p & 0xFFFFu);
              int dy = myy - (int)(p >> 16);
              if (dx * dx + dy * dy <= 100) {
                if (nc < CONFL_MAX) confl[tid * CONFL_MAX + nc] = (unsigned short)j;
                ++nc;
              }
            }
          }
        }
      }
      if (nc > CONFL_MAX) ovfSh = 1;
    }
    ccnt[tid] = (unsigned char)((nc < CONFL_MAX) ? nc : CONFL_MAX);
    // no higher-ranked conflict => accepted unconditionally (greedy invariant)
    state[tid] = ((unsigned)tid < cn) ? ((nc == 0) ? (unsigned char)1
                                                   : (unsigned char)0)
                                      : (unsigned char)2;
    __syncthreads();
    if (ovfSh == 0) {
      // frontier fixed-point: decide c once all its conflicts are decided.
      // state writes are monotone 0->{1,2}; stale reads only delay, not corrupt.
      unsigned char myst = state[tid];
      const int lbase = tid * CONFL_MAX;
      const int ncl = (int)ccnt[tid];
      for (;;) {
        if (tid == 0) undecSh = 0;
        __syncthreads();
        if (myst == 0) {
          bool anyAcc = false, allRej = true;
          for (int k = 0; k < ncl; ++k) {
            unsigned char st = state[confl[lbase + k]];
            anyAcc = anyAcc || (st == 1);
            allRej = allRej && (st == 2);
          }
          unsigned char ns = anyAcc ? (unsigned char)2
                                    : (allRej ? (unsigned char)1 : (unsigned char)0);
          if (ns != 0) state[tid] = ns;
          myst = ns;
        }
        unsigned long long b = __ballot(myst == 0);
        if ((tid & 63) == 0 && b != 0ULL) atomicAdd(&undecSh, (int)__popcll(b));
        __syncthreads();
        if (undecSh == 0) break;
      }
      // rank-order inclusive prefix over accepted; emit first MAXR roots
      scv[tid] = (myst == 1) ? 1 : 0;
      __syncthreads();
      for (int off = 1; off < 1024; off <<= 1) {
        int v = scv[tid] + ((tid >= off) ? scv[tid - off] : 0);
        __syncthreads();
        scv[tid] = v;
        __syncthreads();
      }
      if (myst == 1) {
        int pos = scv[tid] - 1;
        if (pos < MAXR) rootPid[pos] = ~(unsigned int)s[tid];
      }
      if (tid == 0) {
        int total = scv[CAP - 1];
        nVsh = (total < MAXR) ? total : MAXR;
      }
    } else {
      // fallback (adversarial densities only): verified serial greedy walk
      if (tid < 64) {
        const int lane = tid;
        int rx0 = 16384, ry0 = 16384, rx1 = 16384, ry1 = 16384;
        int rx2 = 16384, ry2 = 16384, rx3 = 16384, ry3 = 16384;
        int n = 0;
        unsigned long long kcur = (cn > 0) ? s[0] : 0ULL;
        for (unsigned int c = 0; c < cn && n < MAXR; ++c) {
          unsigned long long knext = (c + 1 < cn) ? s[c + 1] : 0ULL;
          if (!(kcur >> 63)) break;
          unsigned int pid = ~(unsigned int)kcur;
          int cx = (int)(pid & 1023u), cy = (int)(pid >> 10);
          int d0x = cx - rx0, d0y = cy - ry0;
          int d1x = cx - rx1, d1y = cy - ry1;
          int d2x = cx - rx2, d2y = cy - ry2;
          int d3x = cx - rx3, d3y = cy - ry3;
          int hit = (d0x * d0x + d0y * d0y <= 100) |
                    (d1x * d1x + d1y * d1y <= 100) |
                    (d2x * d2x + d2y * d2y <= 100) |
                    (d3x * d3x + d3y * d3y <= 100);
          if (!__any(hit)) {
            int sl = n >> 6, ll = n & 63;
            if (lane == ll) {
              if (sl == 0)      { rx0 = cx; ry0 = cy; }
              else if (sl == 1) { rx1 = cx; ry1 = cy; }
              else if (sl == 2) { rx2 = cx; ry2 = cy; }
              else              { rx3 = cx; ry3 = cy; }
            }
            if (lane == 0) rootPid[n] = pid;
            n++;
          }
          kcur = knext;
        }
        if (lane == 0) nVsh = n;
      }
    }
    __syncthreads();
    const int nv = nVsh;
    if (tid < MAXR) {
      const int valid = (tid < nv) ? 1 : 0;
      unsigned int pid = valid ? rootPid[tid] : 0u;
      int cx = (int)(pid & 1023u), cy = (int)(pid >> 10);
      out[2 * tid]     = valid ? (float)cx * 4.0f : 0.0f;
      out[2 * tid + 1] = valid ? (float)cy * 4.0f : 0.0f;
      out[9216 + tid]  = valid ? 1.0f : 0.0f;
      w->rootX[tid] = valid ? cx : 0;
      w->rootY[tid] = valid ? cy : 0;
    }
    if (tid == 0) w->nValid = nv;
  }
  grid.sync();

  // ---- P5: keypoint epilogue — block r handles root r; 34 active lanes ----
  {
    const int r = bid;
    const int nv = w->nValid;
    const bool valid = r < nv;
    if (tid < 34) {
      float kp = 0.0f;
      const int k = tid >> 1;           // keypoint index 0..16
      const int coord = tid & 1;        // 0 = x (plane 1+2k), 1 = y (plane 2+2k)
      if (valid) {
        const int cx = w->rootX[r], cy = w->rootY[r];
        const float z = sqrtf(2.0f) * 1024.0f;
        size_t base = (size_t)(1 + 2 * k + coord) * 1048576u +
                      (size_t)(cy << 10) + (size_t)cx;
        float dv = tanhf(x[base]);
        float cf = coord ? (float)cy : (float)cx;
        // replicate original arithmetic exactly: p = dv*z + cf; dd = p - cf
        float p = dv * z + cf;
        float dd = p - cf;
        float od = __shfl_xor(dd, 1);
        float d = sqrtf(dd * dd + od * od);
        if (d < 2.0f) p = 0.0f;
        kp = p * 4.0f;
      }
      out[512 + r * 34 + tid] = kp;
    }
  }
}

// ------------------------------------------------- legacy fallback path ----
__global__ __launch_bounds__(256) void spm_hist(const float* __restrict__ x,
                                                WS* __restrict__ w) {
  const int base = blockIdx.x << 10;
  const int tid = threadIdx.x;
#pragma unroll
  for (int j = 0; j < 4; ++j) {
    float v = x[base + tid + (j << 8)];
    float s = sigm(v);
    if (s > 0.8f) {
      unsigned int b = __float_as_uint(s);
      unsigned int bin = (b - B0) >> 8;
      if (bin > NBIN - 1) bin = NBIN - 1;
      atomicAdd(&w->hist[bin], 1u);
    }
  }
}

__global__ __launch_bounds__(1024) void spm_cut(WS* __restrict__ w) {
  __shared__ unsigned int sc[1024];
  __shared__ unsigned int cutBinSh;
  __shared__ unsigned int cnSh;
  const int t = threadIdx.x;
  const int base = t << 4;
  unsigned int cnt[16];
  unsigned int chunkSum = 0;
#pragma unroll
  for (int i = 0; i < 16; ++i) { cnt[i] = w->hist[base + i]; chunkSum += cnt[i]; }
  sc[t] = chunkSum;
  __syncthreads();
  for (int off = 1; off < 1024; off <<= 1) {
    unsigned int v = sc[t] + ((t + off < 1024) ? sc[t + off] : 0u);
    __syncthreads();
    sc[t] = v;
    __syncthreads();
  }
  const unsigned int tailBeyond = (t < 1023) ? sc[t + 1] : 0u;
  unsigned int run = tailBeyond;
  unsigned int sufL[16];
  for (int i = 15; i >= 0; --i) {
    w->dstOff[base + i] = run;
    run += cnt[i];
    sufL[i] = run;
  }
  if (t == 0) {
    cutBinSh = 0;
    unsigned int total = sufL[0];
    cnSh = (total < CAP) ? total : CAP;
  }
  __syncthreads();
#pragma unroll
  for (int i = 0; i < 16; ++i) {
    unsigned int nxt = (i < 15) ? sufL[i + 1] : tailBeyond;
    if (sufL[i] >= TARGET && nxt < TARGET) {
      cutBinSh = (unsigned)(base + i);
      cnSh = (sufL[i] < CAP) ? sufL[i] : CAP;
    }
  }
  __syncthreads();
  if (t == 0) {
    w->cutBits = B0 + (cutBinSh << 8);
    w->candCount = cnSh;
  }
}

__global__ __launch_bounds__(256) void spm_compact(const float* __restrict__ x,
                                                   WS* __restrict__ w) {
  const unsigned int cb = w->cutBits;
  const int base = blockIdx.x << 10;
  const int tid = threadIdx.x;
#pragma unroll
  for (int j = 0; j < 4; ++j) {
    int p = base + tid + (j << 8);
    float v = x[p];
    float s = sigm(v);
    if (s > 0.8f) {
      unsigned int b = __float_as_uint(s);
      if (b >= cb) {
        unsigned int bin = (b - B0) >> 8;
        if (bin > NBIN - 1) bin = NBIN - 1;
        unsigned int pos = atomicAdd(&w->dstOff[bin], 1u);
        if (pos < CAP)
          w->cand[pos] =
              ((unsigned long long)(b | 0x80000000u) << 32) | (unsigned int)(~p);
      }
    }
  }
}

__global__ __launch_bounds__(1024) void spm_walk(WS* __restrict__ w,
                                                 float* __restrict__ out) {
  __shared__ unsigned long long s[CAP];
  __shared__ unsigned short binA[CAP];
  __shared__ unsigned int pxy[CAP];
  __shared__ int cellCnt[1024];
  __shared__ unsigned short cellList[1024 * CELL_CAP];
  __shared__ unsigned short confl[CAP * CONFL_MAX];
  __shared__ unsigned char ccnt[CAP];
  __shared__ unsigned char state[CAP];
  __shared__ int scv[CAP];
  __shared__ unsigned int rootPid[MAXR];
  __shared__ int nVsh;
  __shared__ int undecSh;
  __shared__ int ovfSh;
  const int tid = threadIdx.x;
  unsigned int cn = w->candCount;
  if (cn > CAP) cn = CAP;
  if ((unsigned)tid < cn) {
    unsigned long long k = w->cand[tid];
    s[tid] = k;
    binA[tid] = (unsigned short)(((unsigned int)(k >> 32) - KEYB0) >> 8);
  } else {
    s[tid] = 0ULL;
    binA[tid] = 0xFFFFu;
  }
  if (tid == 0) ovfSh = 0;
  cellCnt[tid] = 0;
  __syncthreads();
  const bool isStart =
      ((unsigned)tid < cn) && (tid == 0 || binA[tid] != binA[tid - 1]);
  if (isStart) {
    const unsigned short mybin = binA[tid];
    int e = tid + 1;
    while (e < (int)cn && binA[e] == mybin) ++e;
    for (int j = tid + 1; j < e; ++j) {
      unsigned long long key = s[j];
      int i2 = j - 1;
      while (i2 >= tid && s[i2] < key) { s[i2 + 1] = s[i2]; --i2; }
      s[i2 + 1] = key;
    }
  }
  __syncthreads();
  int myx = 0, myy = 0;
  if ((unsigned)tid < cn) {
    unsigned int pid = ~(unsigned int)s[tid];
    myx = (int)(pid & 1023u);
    myy = (int)(pid >> 10);
    pxy[tid] = (unsigned int)myx | ((unsigned int)myy << 16);
    int cell = ((myy >> 5) << 5) | (myx >> 5);
    int pos = atomicAdd(&cellCnt[cell], 1);
    if (pos < CELL_CAP) cellList[cell * CELL_CAP + pos] = (unsigned short)tid;
    else ovfSh = 1;
  }
  __syncthreads();
  int nc = 0;
  if ((unsigned)tid < cn) {
    int cy0 = (myy >= 10) ? ((myy - 10) >> 5) : 0;
    int cy1 = (((myy + 10) < 1023) ? (myy + 10) : 1023) >> 5;
    int cx0 = (myx >= 10) ? ((myx - 10) >> 5) : 0;
    int cx1 = (((myx + 10) < 1023) ? (myx + 10) : 1023) >> 5;
    for (int cyc = cy0; cyc <= cy1; ++cyc) {
      for (int cxc = cx0; cxc <= cx1; ++cxc) {
        int cell = (cyc << 5) | cxc;
        int cnt2 = cellCnt[cell];
        if (cnt2 > CELL_CAP) cnt2 = CELL_CAP;
        for (int e = 0; e < cnt2; ++e) {
          int j = (int)cellList[cell * CELL_CAP + e];
          if (j < tid) {
            unsigned int p = pxy[j];
            int dx = myx - (int)(p & 0xFFFFu);
            int dy = myy - (int)(p >> 16);
            if (dx * dx + dy * dy <= 100) {
              if (nc < CONFL_MAX) confl[tid * CONFL_MAX + nc] = (unsigned short)j;
              ++nc;
            }
          }
        }
      }
    }
    if (nc > CONFL_MAX) ovfSh = 1;
  }
  ccnt[tid] = (unsigned char)((nc < CONFL_MAX) ? nc : CONFL_MAX);
  state[tid] = ((unsigned)tid < cn) ? ((nc == 0) ? (unsigned char)1
                                                 : (unsigned char)0)
                                    : (unsigned char)2;
  __syncthreads();
  if (ovfSh == 0) {
    unsigned char myst = state[tid];
    const int lbase = tid * CONFL_MAX;
    const int ncl = (int)ccnt[tid];
    for (;;) {
      if (tid == 0) undecSh = 0;
      __syncthreads();
      if (myst == 0) {
        bool anyAcc = false, allRej = true;
        for (int k = 0; k < ncl; ++k) {
          unsigned char st = state[confl[lbase + k]];
          anyAcc = anyAcc || (st == 1);
          allRej = allRej && (st == 2);
        }
        unsigned char ns = anyAcc ? (unsigned char)2
                                  : (allRej ? (unsigned char)1 : (unsigned char)0);
        if (ns != 0) state[tid] = ns;
        myst = ns;
      }
      unsigned long long b = __ballot(myst == 0);
      if ((tid & 63) == 0 && b != 0ULL) atomicAdd(&undecSh, (int)__popcll(b));
      __syncthreads();
      if (undecSh == 0) break;
    }
    scv[tid] = (myst == 1) ? 1 : 0;
    __syncthreads();
    for (int off = 1; off < 1024; off <<= 1) {
      int v = scv[tid] + ((tid >= off) ? scv[tid - off] : 0);
      __syncthreads();
      scv[tid] = v;
      __syncthreads();
    }
    if (myst == 1) {
      int pos = scv[tid] - 1;
      if (pos < MAXR) rootPid[pos] = ~(unsigned int)s[tid];
    }
    if (tid == 0) {
      int total = scv[CAP - 1];
      nVsh = (total < MAXR) ? total : MAXR;
    }
  } else {
    if (tid < 64) {
      const int lane = tid;
      int rx0 = 16384, ry0 = 16384, rx1 = 16384, ry1 = 16384;
      int rx2 = 16384, ry2 = 16384, rx3 = 16384, ry3 = 16384;
      int n = 0;
      unsigned long long kcur = (cn > 0) ? s[0] : 0ULL;
      for (unsigned int c = 0; c < cn && n < MAXR; ++c) {
        unsigned long long knext = (c + 1 < cn) ? s[c + 1] : 0ULL;
        if (!(kcur >> 63)) break;
        unsigned int pid = ~(unsigned int)kcur;
        int cx = (int)(pid & 1023u), cy = (int)(pid >> 10);
        int d0x = cx - rx0, d0y = cy - ry0;
        int d1x = cx - rx1, d1y = cy - ry1;
        int d2x = cx - rx2, d2y = cy - ry2;
        int d3x = cx - rx3, d3y = cy - ry3;
        int hit = (d0x * d0x + d0y * d0y <= 100) |
                  (d1x * d1x + d1y * d1y <= 100) |
                  (d2x * d2x + d2y * d2y <= 100) |
                  (d3x * d3x + d3y * d3y <= 100);
        if (!__any(hit)) {
          int sl = n >> 6, ll = n & 63;
          if (lane == ll) {
            if (sl == 0)      { rx0 = cx; ry0 = cy; }
            else if (sl == 1) { rx1 = cx; ry1 = cy; }
            else if (sl == 2) { rx2 = cx; ry2 = cy; }
            else              { rx3 = cx; ry3 = cy; }
          }
          if (lane == 0) rootPid[n] = pid;
          n++;
        }
        kcur = knext;
      }
      if (lane == 0) nVsh = n;
    }
  }
  __syncthreads();
  const int nv = nVsh;
  if (tid < MAXR) {
    const int valid = (tid < nv) ? 1 : 0;
    unsigned int pid = valid ? rootPid[tid] : 0u;
    int cx = (int)(pid & 1023u), cy = (int)(pid >> 10);
    out[2 * tid]     = valid ? (float)cx * 4.0f : 0.0f;
    out[2 * tid + 1] = valid ? (float)cy * 4.0f : 0.0f;
    out[9216 + tid]  = valid ? 1.0f : 0.0f;
    w->rootX[tid] = valid ? cx : 0;
    w->rootY[tid] = valid ? cy : 0;
  }
  if (tid == 0) w->nValid = nv;
}

__global__ __launch_bounds__(64) void spm_kp(const float* __restrict__ x,
                                             const WS* __restrict__ w,
                                             float* __restrict__ out) {
  const int r = blockIdx.x;
  const int lane = threadIdx.x;
  const int nv = w->nValid;
  const bool valid = r < nv;
  const int cx = w->rootX[r], cy = w->rootY[r];
  if (lane < 17) {
    float kpx = 0.0f, kpy = 0.0f;
    if (valid) {
      const float z = sqrtf(2.0f) * 1024.0f;
      size_t base = (size_t)(1 + 2 * lane) * 1048576u + (size_t)(cy << 10) + (size_t)cx;
      float dvx = tanhf(x[base]);
      float dvy = tanhf(x[base + 1048576u]);
      float cxf = (float)cx, cyf = (float)cy;
      float px = dvx * z + cxf;
      float py = dvy * z + cyf;
      float ddx = px - cxf, ddy = py - cyf;
      float d = sqrtf(ddx * ddx + ddy * ddy);
      if (d < 2.0f) { px = 0.0f; py = 0.0f; }
      kpx = px * 4.0f;
      kpy = py * 4.0f;
    }
    out[512 + r * 34 + 2 * lane]     = kpx;
    out[512 + r * 34 + 2 * lane + 1] = kpy;
  }
}

extern "C" void kernel_launch(void* const* d_in, const int* in_sizes, int n_in,
                              void* d_out, int out_size, void* d_ws, size_t ws_size,
                              hipStream_t stream) {
  const float* x = (const float*)d_in[0];
  float* out = (float*)d_out;
  WS* w = (WS*)d_ws;

  void* args[] = {(void*)&x, (void*)&w, (void*)&out};
  hipError_t rc = hipLaunchCooperativeKernel((const void*)spm_fused, dim3(256),
                                             dim3(1024), args, 0, stream);
  if (rc != hipSuccess) {
    // verified 6-dispatch fallback (R5 path)
    hipMemsetAsync(d_ws, 0, NBIN * sizeof(unsigned int), stream);
    spm_hist<<<1024, 256, 0, stream>>>(x, w);
    spm_cut<<<1, 1024, 0, stream>>>(w);
    spm_compact<<<1024, 256, 0, stream>>>(x, w);
    spm_walk<<<1, 1024, 0, stream>>>(w, out);
    spm_kp<<<MAXR, 64, 0, stream>>>(x, w, out);
  }
}

// Round 4
// 196.033 us; speedup vs baseline: 1.6073x; 1.6073x over previous
//
#include <hip/hip_runtime.h>
#include <math.h>

// DecodeSPM on gfx950 — round 8: revert cooperative fusion (R7 post-mortem:
// grid.sync() costs ~28us each on 8-XCD gfx950 — 5 syncs = 142us kernel with
// VALUBusy 0.9%; dispatch boundaries are CHEAPER). Back to the verified R5
// 6-dispatch chain, with barrier-count surgery on the single-block kernels:
//   - spm_cut: 1024-wide LDS suffix scan (20 barriers) -> wave-shfl
//     hierarchical suffix scan (2 barriers); uint4 hist loads.
//   - spm_walk: 1024-wide rank prefix scan (20 barriers) -> wave-shfl
//     hierarchical prefix scan (1 barrier); -4KB LDS.
//   - hist/compact: float4 input loads (4 px per 16B transaction).
// Timed-region model: ~178us harness poison fills (2 x ~89us) + ~20us chain;
// this round targets the chain.
//  memset:     clear 16K-bin histogram (64 KB).
//  K1 hist:    sigmoid(ch0), conf>0.8 -> global atomic histogram of bits>>8.
//  K2 cut:     suffix-scan 16K bins -> cutoff keeping top >=768 keys, per-bin
//              descending scatter offsets, candCount.
//  K3 compact: scatter keys (confbits|msb)<<32 | ~pid into bin-bucketed
//              globally-descending order.
//  K4 walk:    1 block: per-bin insertion sorts (exact full-key order) ->
//              cell-hash conflict lists -> frontier NMS (exact greedy set,
//              serial fallback on overflow) -> prefix-scan emit.
//  K5 kp:      256 blocks: gather tanh displacements, keypoint epilogue.

#define SS 1024
#define MAXR 256
#define NBIN 16384
#define CAP 1024
#define TARGET 768u
#define B0 0x3F4CCCCEu     // smallest f32 bit pattern with s > 0.8f
#define KEYB0 0xBF4CCCCEu  // B0 | 0x80000000
#define CONFL_MAX 8
#define CELL_CAP 8

struct WS {
  unsigned int hist[NBIN];
  unsigned int dstOff[NBIN];
  unsigned int cutBits;
  unsigned int candCount;
  int nValid;
  int pad0;
  int rootX[MAXR];
  int rootY[MAXR];
  unsigned long long cand[CAP];
};

__device__ __forceinline__ float sigm(float v) {
  return 1.0f / (1.0f + expf(-v));
}

__global__ __launch_bounds__(256) void spm_hist(const float* __restrict__ x,
                                                WS* __restrict__ w) {
  const int i4 = (blockIdx.x << 8) + threadIdx.x;  // 0..262143
  const float4 v4 = ((const float4*)x)[i4];
  const float vv[4] = {v4.x, v4.y, v4.z, v4.w};
#pragma unroll
  for (int j = 0; j < 4; ++j) {
    float s = sigm(vv[j]);
    if (s > 0.8f) {
      unsigned int b = __float_as_uint(s);
      unsigned int bin = (b - B0) >> 8;
      if (bin > NBIN - 1) bin = NBIN - 1;
      atomicAdd(&w->hist[bin], 1u);
    }
  }
}

__global__ __launch_bounds__(1024) void spm_cut(WS* __restrict__ w) {
  __shared__ unsigned int wtot[16];
  __shared__ unsigned int cutBinSh;
  __shared__ unsigned int cnSh;
  const int t = threadIdx.x;
  const int lane = t & 63;
  const int wv = t >> 6;
  const int base = t << 4;
  unsigned int cnt[16];
  unsigned int chunkSum = 0;
  const uint4* h4 = (const uint4*)(&w->hist[base]);
#pragma unroll
  for (int i = 0; i < 4; ++i) {
    uint4 q = h4[i];
    cnt[4 * i + 0] = q.x; cnt[4 * i + 1] = q.y;
    cnt[4 * i + 2] = q.z; cnt[4 * i + 3] = q.w;
    chunkSum += q.x + q.y + q.z + q.w;
  }
  // in-wave inclusive suffix scan of chunk sums (no barriers)
  unsigned int v = chunkSum;
#pragma unroll
  for (int off = 1; off < 64; off <<= 1) {
    unsigned int o = __shfl_down(v, off);
    if (lane + off < 64) v += o;
  }
  if (lane == 0) wtot[wv] = v;  // total of this wave's 64 chunks
  __syncthreads();
  unsigned int wtail = 0;       // keys in waves after this one
#pragma unroll
  for (int i = 0; i < 16; ++i)
    if (i > wv) wtail += wtot[i];
  unsigned int nxtInWave = __shfl_down(v, 1);
  const unsigned int tailBeyond = (lane < 63) ? (nxtInWave + wtail) : wtail;
  unsigned int run = tailBeyond;
  unsigned int sufL[16];
  for (int i = 15; i >= 0; --i) {
    w->dstOff[base + i] = run;   // = #keys in bins > base+i (descending order)
    run += cnt[i];
    sufL[i] = run;               // = #keys in bins >= base+i
  }
  if (t == 0) {
    cutBinSh = 0;
    unsigned int total = v + wtail;  // grand total (suffix at chunk 0)
    cnSh = (total < CAP) ? total : CAP;
  }
  __syncthreads();
#pragma unroll
  for (int i = 0; i < 16; ++i) {
    unsigned int nxt = (i < 15) ? sufL[i + 1] : tailBeyond;
    if (sufL[i] >= TARGET && nxt < TARGET) {  // unique crossing (monotone)
      cutBinSh = (unsigned)(base + i);
      cnSh = (sufL[i] < CAP) ? sufL[i] : CAP;
    }
  }
  __syncthreads();
  if (t == 0) {
    w->cutBits = B0 + (cutBinSh << 8);
    w->candCount = cnSh;
  }
}

__global__ __launch_bounds__(256) void spm_compact(const float* __restrict__ x,
                                                   WS* __restrict__ w) {
  const unsigned int cb = w->cutBits;
  const int i4 = (blockIdx.x << 8) + threadIdx.x;
  const float4 v4 = ((const float4*)x)[i4];
  const float vv[4] = {v4.x, v4.y, v4.z, v4.w};
#pragma unroll
  for (int j = 0; j < 4; ++j) {
    float s = sigm(vv[j]);
    if (s > 0.8f) {
      unsigned int b = __float_as_uint(s);
      if (b >= cb) {
        int p = (i4 << 2) + j;
        unsigned int bin = (b - B0) >> 8;
        if (bin > NBIN - 1) bin = NBIN - 1;
        unsigned int pos = atomicAdd(&w->dstOff[bin], 1u);
        if (pos < CAP)
          w->cand[pos] =
              ((unsigned long long)(b | 0x80000000u) << 32) | (unsigned int)(~p);
      }
    }
  }
}

__global__ __launch_bounds__(1024) void spm_walk(WS* __restrict__ w,
                                                 float* __restrict__ out) {
  __shared__ unsigned long long s[CAP];
  __shared__ unsigned short binA[CAP];
  __shared__ unsigned int pxy[CAP];
  __shared__ int cellCnt[1024];                      // 32x32 grid of 32px cells
  __shared__ unsigned short cellList[1024 * CELL_CAP];
  __shared__ unsigned short confl[CAP * CONFL_MAX];  // higher-ranked conflicts
  __shared__ unsigned char ccnt[CAP];
  __shared__ unsigned char state[CAP];               // 0 undec, 1 acc, 2 rej
  __shared__ int wsum[16];
  __shared__ unsigned int rootPid[MAXR];
  __shared__ int nVsh;
  __shared__ int undecSh;
  __shared__ int ovfSh;
  const int tid = threadIdx.x;
  const int lane = tid & 63;
  const int wv = tid >> 6;
  unsigned int cn = w->candCount;
  if (cn > CAP) cn = CAP;
  if ((unsigned)tid < cn) {
    unsigned long long k = w->cand[tid];
    s[tid] = k;
    binA[tid] = (unsigned short)(((unsigned int)(k >> 32) - KEYB0) >> 8);
  } else {
    s[tid] = 0ULL;
    binA[tid] = 0xFFFFu;
  }
  if (tid == 0) ovfSh = 0;
  cellCnt[tid] = 0;
  __syncthreads();
  // per-bin insertion sort (descending, full 64-bit key). Disjoint segments;
  // binA is read-only past this point, so boundary checks are race-free.
  const bool isStart =
      ((unsigned)tid < cn) && (tid == 0 || binA[tid] != binA[tid - 1]);
  if (isStart) {
    const unsigned short mybin = binA[tid];
    int e = tid + 1;
    while (e < (int)cn && binA[e] == mybin) ++e;
    for (int j = tid + 1; j < e; ++j) {
      unsigned long long key = s[j];
      int i2 = j - 1;
      while (i2 >= tid && s[i2] < key) { s[i2 + 1] = s[i2]; --i2; }
      s[i2 + 1] = key;
    }
  }
  __syncthreads();
  // decode positions; hash into 32px cells (radius 10 spans <=2 cells/axis)
  int myx = 0, myy = 0;
  if ((unsigned)tid < cn) {
    unsigned int pid = ~(unsigned int)s[tid];
    myx = (int)(pid & 1023u);
    myy = (int)(pid >> 10);
    pxy[tid] = (unsigned int)myx | ((unsigned int)myy << 16);
    int cell = ((myy >> 5) << 5) | (myx >> 5);
    int pos = atomicAdd(&cellCnt[cell], 1);
    if (pos < CELL_CAP) cellList[cell * CELL_CAP + pos] = (unsigned short)tid;
    else ovfSh = 1;
  }
  __syncthreads();
  // conflict lists: higher-ranked (smaller index) candidates within d^2<=100
  int nc = 0;
  if ((unsigned)tid < cn) {
    int cy0 = (myy >= 10) ? ((myy - 10) >> 5) : 0;
    int cy1 = (((myy + 10) < 1023) ? (myy + 10) : 1023) >> 5;
    int cx0 = (myx >= 10) ? ((myx - 10) >> 5) : 0;
    int cx1 = (((myx + 10) < 1023) ? (myx + 10) : 1023) >> 5;
    for (int cyc = cy0; cyc <= cy1; ++cyc) {
      for (int cxc = cx0; cxc <= cx1; ++cxc) {
        int cell = (cyc << 5) | cxc;
        int cnt2 = cellCnt[cell];
        if (cnt2 > CELL_CAP) cnt2 = CELL_CAP;
        for (int e = 0; e < cnt2; ++e) {
          int j = (int)cellList[cell * CELL_CAP + e];
          if (j < tid) {
            unsigned int p = pxy[j];
            int dx = myx - (int)(p & 0xFFFFu);
            int dy = myy - (int)(p >> 16);
            if (dx * dx + dy * dy <= 100) {
              if (nc < CONFL_MAX) confl[tid * CONFL_MAX + nc] = (unsigned short)j;
              ++nc;
            }
          }
        }
      }
    }
    if (nc > CONFL_MAX) ovfSh = 1;
  }
  ccnt[tid] = (unsigned char)((nc < CONFL_MAX) ? nc : CONFL_MAX);
  // no higher-ranked conflict => accepted unconditionally (greedy invariant)
  state[tid] = ((unsigned)tid < cn) ? ((nc == 0) ? (unsigned char)1
                                                 : (unsigned char)0)
                                    : (unsigned char)2;
  __syncthreads();
  if (ovfSh == 0) {
    // frontier fixed-point: decide c once all its conflicts are decided.
    // state writes are monotone 0->{1,2}; stale reads only delay, not corrupt.
    unsigned char myst = state[tid];
    const int lbase = tid * CONFL_MAX;
    const int ncl = (int)ccnt[tid];
    for (;;) {
      if (tid == 0) undecSh = 0;
      __syncthreads();
      if (myst == 0) {
        bool anyAcc = false, allRej = true;
        for (int k = 0; k < ncl; ++k) {
          unsigned char st = state[confl[lbase + k]];
          anyAcc = anyAcc || (st == 1);
          allRej = allRej && (st == 2);
        }
        unsigned char ns = anyAcc ? (unsigned char)2
                                  : (allRej ? (unsigned char)1 : (unsigned char)0);
        if (ns != 0) state[tid] = ns;
        myst = ns;
      }
      unsigned long long b = __ballot(myst == 0);
      if ((tid & 63) == 0 && b != 0ULL) atomicAdd(&undecSh, (int)__popcll(b));
      __syncthreads();
      if (undecSh == 0) break;
    }
    // rank-order inclusive prefix over accepted (wave-shfl hierarchical scan)
    int pv = (myst == 1) ? 1 : 0;
#pragma unroll
    for (int off = 1; off < 64; off <<= 1) {
      int o = __shfl_up(pv, off);
      if (lane >= off) pv += o;
    }
    if (lane == 63) wsum[wv] = pv;  // wave totals
    __syncthreads();
    int wpre = 0;
#pragma unroll
    for (int i = 0; i < 16; ++i)
      if (i < wv) wpre += wsum[i];
    if (myst == 1) {
      int pos = pv + wpre - 1;     // inclusive prefix - 1 = rank
      if (pos < MAXR) rootPid[pos] = ~(unsigned int)s[tid];
    }
    if (tid == 0) {
      int total = 0;
#pragma unroll
      for (int i = 0; i < 16; ++i) total += wsum[i];
      nVsh = (total < MAXR) ? total : MAXR;
    }
  } else {
    // fallback (adversarial densities only): verified serial greedy walk
    if (tid < 64) {
      int rx0 = 16384, ry0 = 16384, rx1 = 16384, ry1 = 16384;
      int rx2 = 16384, ry2 = 16384, rx3 = 16384, ry3 = 16384;
      int n = 0;
      unsigned long long kcur = (cn > 0) ? s[0] : 0ULL;
      for (unsigned int c = 0; c < cn && n < MAXR; ++c) {
        unsigned long long knext = (c + 1 < cn) ? s[c + 1] : 0ULL;
        if (!(kcur >> 63)) break;
        unsigned int pid = ~(unsigned int)kcur;
        int cx = (int)(pid & 1023u), cy = (int)(pid >> 10);
        int d0x = cx - rx0, d0y = cy - ry0;
        int d1x = cx - rx1, d1y = cy - ry1;
        int d2x = cx - rx2, d2y = cy - ry2;
        int d3x = cx - rx3, d3y = cy - ry3;
        int hit = (d0x * d0x + d0y * d0y <= 100) |
                  (d1x * d1x + d1y * d1y <= 100) |
                  (d2x * d2x + d2y * d2y <= 100) |
                  (d3x * d3x + d3y * d3y <= 100);
        if (!__any(hit)) {
          int sl = n >> 6, ll = n & 63;
          if (lane == ll) {
            if (sl == 0)      { rx0 = cx; ry0 = cy; }
            else if (sl == 1) { rx1 = cx; ry1 = cy; }
            else if (sl == 2) { rx2 = cx; ry2 = cy; }
            else              { rx3 = cx; ry3 = cy; }
          }
          if (lane == 0) rootPid[n] = pid;
          n++;
        }
        kcur = knext;
      }
      if (lane == 0) nVsh = n;
    }
  }
  __syncthreads();
  const int nv = nVsh;
  if (tid < MAXR) {
    const int valid = (tid < nv) ? 1 : 0;
    unsigned int pid = valid ? rootPid[tid] : 0u;
    int cx = (int)(pid & 1023u), cy = (int)(pid >> 10);
    out[2 * tid]     = valid ? (float)cx * 4.0f : 0.0f;
    out[2 * tid + 1] = valid ? (float)cy * 4.0f : 0.0f;
    out[9216 + tid]  = valid ? 1.0f : 0.0f;
    w->rootX[tid] = valid ? cx : 0;
    w->rootY[tid] = valid ? cy : 0;
  }
  if (tid == 0) w->nValid = nv;
}

__global__ __launch_bounds__(64) void spm_kp(const float* __restrict__ x,
                                             const WS* __restrict__ w,
                                             float* __restrict__ out) {
  const int r = blockIdx.x;
  const int lane = threadIdx.x;
  const int nv = w->nValid;
  const bool valid = r < nv;
  const int cx = w->rootX[r], cy = w->rootY[r];
  if (lane < 17) {
    float kpx = 0.0f, kpy = 0.0f;
    if (valid) {
      const float z = sqrtf(2.0f) * 1024.0f;
      size_t base = (size_t)(1 + 2 * lane) * 1048576u + (size_t)(cy << 10) + (size_t)cx;
      float dvx = tanhf(x[base]);
      float dvy = tanhf(x[base + 1048576u]);
      float cxf = (float)cx, cyf = (float)cy;
      float px = dvx * z + cxf;
      float py = dvy * z + cyf;
      float ddx = px - cxf, ddy = py - cyf;
      float d = sqrtf(ddx * ddx + ddy * ddy);
      if (d < 2.0f) { px = 0.0f; py = 0.0f; }
      kpx = px * 4.0f;
      kpy = py * 4.0f;
    }
    out[512 + r * 34 + 2 * lane]     = kpx;
    out[512 + r * 34 + 2 * lane + 1] = kpy;
  }
}

extern "C" void kernel_launch(void* const* d_in, const int* in_sizes, int n_in,
                              void* d_out, int out_size, void* d_ws, size_t ws_size,
                              hipStream_t stream) {
  const float* x = (const float*)d_in[0];
  float* out = (float*)d_out;
  WS* w = (WS*)d_ws;

  hipMemsetAsync(d_ws, 0, NBIN * sizeof(unsigned int), stream);  // hist only
  spm_hist<<<1024, 256, 0, stream>>>(x, w);
  spm_cut<<<1, 1024, 0, stream>>>(w);
  spm_compact<<<1024, 256, 0, stream>>>(x, w);
  spm_walk<<<1, 1024, 0, stream>>>(w, out);
  spm_kp<<<MAXR, 64, 0, stream>>>(x, w, out);
}